// Round 7
// baseline (119.408 us; speedup 1.0000x reference)
//
#include <hip/hip_runtime.h>
#include <math.h>

// Fused SIFT-like pipeline:
//   Sobel(3x3, pad1) -> project onto 8 orientations -> argmax -> magnitude
//   into winning bin -> depthwise 4x4 ones conv (pad2) => out (8,8,1025,1025)
//
// v7: FULL-ROW band blocks for HBM write page locality.
//   block = 576 threads (9 waves); wave = 124-col strip (2 cols/lane);
//   block covers out rows [r0, r0+33) x cols 0..1024 -> each plane-row's
//   4100 B is written by 9 near-lockstep waves of one block in a tight
//   burst (page hits), instead of 17 scattered blocks (v6).
//   No LDS, no barriers: x read as 2 aligned float2 global loads/lane/row
//   (L2-resident per XCD via batch==XCD swizzle) + DPP seam exchange,
//   1-row load lookahead. Compute = v6's exact f32 trees x 2 cols.
//
// Per lane: hist cols h0=j0-2+2l, h0+1; out cols oc0=j0+2l, oc0+1.
// out_even = S_l + S_{l+1};  out_odd = B_l + S_{l+1} + A_{l+2}
// (A,B = vertical 4-sums of the lane's 2 hist cols, S=A+B; neighbor
//  values via chained DPP wave_shl:1; lanes 62,63 feed only).

#define BROWS 33            // out rows per band
#define NBANDS 32           // 32*33 = 1056 >= 1025
#define STRIPW 124          // out cols per wave strip
#define PLANE 1050625       // 1025*1025

// DPP wave_shl:1: lane i <- lane i+1, zero-fill at lane 63 (== shfl_down 1)
__device__ __forceinline__ float wshl1(float v) {
    return __int_as_float(
        __builtin_amdgcn_update_dpp(0, __float_as_int(v), 0x130, 0xf, 0xf, true));
}

__global__ __launch_bounds__(576, 3)
void sift_fused(const float* __restrict__ x,
                const float* __restrict__ ow,
                float* __restrict__ out)
{
    const int tid  = threadIdx.x;
    const int lane = tid & 63;
    const int wv   = tid >> 6;

    // XCD-aware: batch == XCD (grid 32x8 -> flat 0..255, bijective)
    const int flat = blockIdx.x + NBANDS * blockIdx.y;
    const int bb   = flat & 7;
    const int band = flat >> 3;
    const int r0 = band * BROWS;
    const int j0 = wv * STRIPW;

    const float* xb = x + (size_t)bb * 1024 * 1024;

    // orientation weights (uniform loads; exact argmax vs reference)
    float wcn[8], wsn[8];
    #pragma unroll
    for (int o = 0; o < 8; ++o) { wcn[o] = ow[2*o]; wsn[o] = ow[2*o+1]; }

    // x gather geometry: lane needs x cols c1+1..c1+3 (B,C,D) + E from DPP
    const int c1 = j0 - 4 + 2*lane;
    const int s1 = min(max(c1,     0), 1022);   // even -> 8B aligned
    const int s2 = min(max(c1 + 2, 0), 1022);
    const float mB = ((unsigned)(c1+1) < 1024u) ? 1.f : 0.f;
    const float mC = ((unsigned)(c1+2) < 1024u) ? 1.f : 0.f;
    const float mD = ((unsigned)(c1+3) < 1024u) ? 1.f : 0.f;

    // hist col validity
    const int h0 = j0 - 2 + 2*lane;
    const float cm0 = ((unsigned)h0     < 1024u) ? 1.f : 0.f;
    const float cm1 = ((unsigned)(h0+1) < 1024u) ? 1.f : 0.f;

    // store predicates
    const int oc0 = j0 + 2*lane;
    const bool st0 = (2*lane   < STRIPW) && (oc0   <= 1024);
    const bool st1 = (2*lane+1 < STRIPW) && (oc0+1 <= 1024);

    // per-channel plane base pointers (uniform)
    float* po[8];
    #pragma unroll
    for (int o = 0; o < 8; ++o) po[o] = out + (size_t)(bb*8 + o) * PLANE;

    int vo   = r0 * 1025 + oc0;
    int orow = r0;
    int gr   = r0 - 3;          // next x row to issue
    int hrow = r0 - 2;          // hist row of current HSTEP

    // state: d/w x-row rings [slot][col], one-hot ping-pong, pair-sum ring
    float RD[4][2], RW[4][2];
    float CEXP[2][2][8];
    float PP[4][2][8];
    float2 pv1, pv2;            // in-flight x loads (1-row lookahead)

// issue loads for x row gr (or zeros), advance gr
#define XISSUE() { \
    if ((unsigned)gr < 1024u) { \
        const float* rp = xb + ((size_t)(unsigned)gr << 10); \
        pv1 = *reinterpret_cast<const float2*>(rp + s1); \
        pv2 = *reinterpret_cast<const float2*>(rp + s2); \
    } else { pv1.x = 0.f; pv1.y = 0.f; pv2.x = 0.f; pv2.y = 0.f; } \
    gr++; \
}

// commit pending loads into ring slot SB (masked cols, DPP seam)
#define XCOMMIT(SB) { \
    float B_ = pv1.y * mB, C_ = pv2.x * mC, D_ = pv2.y * mD; \
    float E_ = wshl1(C_); \
    RD[SB][0] = D_ - B_; \
    RD[SB][1] = E_ - C_; \
    RW[SB][0] = B_ + 2.0f*C_ + D_; \
    RW[SB][1] = C_ + 2.0f*D_ + E_; \
}

// tournament argmax: identical semantics to sequential first-max
#define TOURN8(RES, GX, GY) { \
    float pj0 = (GX)*wcn[0] + (GY)*wsn[0]; \
    float pj1 = (GX)*wcn[1] + (GY)*wsn[1]; \
    float pj2 = (GX)*wcn[2] + (GY)*wsn[2]; \
    float pj3 = (GX)*wcn[3] + (GY)*wsn[3]; \
    float pj4 = (GX)*wcn[4] + (GY)*wsn[4]; \
    float pj5 = (GX)*wcn[5] + (GY)*wsn[5]; \
    float pj6 = (GX)*wcn[6] + (GY)*wsn[6]; \
    float pj7 = (GX)*wcn[7] + (GY)*wsn[7]; \
    bool g01 = pj1 > pj0; float b01 = g01 ? pj1 : pj0; int i01 = g01 ? 1 : 0; \
    bool g23 = pj3 > pj2; float b23 = g23 ? pj3 : pj2; int i23 = g23 ? 3 : 2; \
    bool g45 = pj5 > pj4; float b45 = g45 ? pj5 : pj4; int i45 = g45 ? 5 : 4; \
    bool g67 = pj7 > pj6; float b67 = g67 ? pj7 : pj6; int i67 = g67 ? 7 : 6; \
    bool gA = b23 > b01; float bA = gA ? b23 : b01; int iA = gA ? i23 : i01; \
    bool gB = b67 > b45; float bB = gB ? b67 : b45; int iB = gB ? i67 : i45; \
    RES = (bB > bA) ? iB : iA; \
}

// one hist row: commit x row j+2, issue j+3, Sobel both cols, argmax,
// expansion; pair sum into PP[PW]; optional FIN of out row j-3 using PP[PRD].
#define HSTEP(ST, SM, SB, EC, EP, PW, PRD, DOP, DOFIN) { \
    XCOMMIT(SB) \
    XISSUE() \
    float rowm = ((unsigned)hrow < 1024u) ? 1.f : 0.f; \
    hrow++; \
    _Pragma("unroll") \
    for (int c_ = 0; c_ < 2; ++c_) { \
        float gx = RD[ST][c_] + 2.0f*RD[SM][c_] + RD[SB][c_]; \
        float gy = RW[SB][c_] - RW[ST][c_]; \
        float m = __builtin_amdgcn_sqrtf(gx*gx + gy*gy) \
                    * (rowm * (c_ ? cm1 : cm0)); \
        int idx_; \
        TOURN8(idx_, gx, gy) \
        _Pragma("unroll") \
        for (int o = 0; o < 8; ++o) \
            CEXP[EC][c_][o] = (idx_ == o) ? m : 0.0f; \
    } \
    if (DOP) { \
        _Pragma("unroll") \
        for (int c_ = 0; c_ < 2; ++c_) { \
            _Pragma("unroll") \
            for (int o = 0; o < 8; ++o) \
                PP[PW][c_][o] = CEXP[EP][c_][o] + CEXP[EC][c_][o]; \
        } \
    } \
    if (DOFIN) { \
        bool rowok = (orow <= 1024); \
        _Pragma("unroll") \
        for (int o = 0; o < 8; ++o) { \
            float A  = PP[PRD][0][o] + PP[PW][0][o]; \
            float Bv = PP[PRD][1][o] + PP[PW][1][o]; \
            float S  = A + Bv; \
            float Sd = wshl1(S); \
            float Ad2 = wshl1(wshl1(A)); \
            float Ev = S + Sd; \
            float Ov = Bv + Sd + Ad2; \
            if (rowok && st0) po[o][vo]   = Ev; \
            if (rowok && st1) po[o][vo+1] = Ov; \
        } \
        vo += 1025; orow++; \
    } \
}

    // prologue: x rows r0-3, r0-2 into slots 0,1 (1-row lookahead pipeline)
    XISSUE()
    XCOMMIT(0) XISSUE()
    XCOMMIT(1) XISSUE()
    // hist rows j=0,1,2 (no FIN)
    HSTEP(0,1,2, 0,1, 0,0, 0, 0)    // j=0
    HSTEP(1,2,3, 1,0, 1,3, 1, 0)    // j=1
    HSTEP(2,3,0, 0,1, 2,0, 1, 0)    // j=2

    // steady: j=3..34 (8 QUADs), FIN t=j-3
    #pragma unroll 1
    for (int it = 0; it < 8; ++it) {
        HSTEP(3,0,1, 1,0, 3,1, 1, 1)    // j%4==3
        HSTEP(0,1,2, 0,1, 0,2, 1, 1)    // j%4==0
        HSTEP(1,2,3, 1,0, 1,3, 1, 1)    // j%4==1
        HSTEP(2,3,0, 0,1, 2,0, 1, 1)    // j%4==2
    }
    // j=35 (== 3 mod 4): last FIN -> out row r0+32
    HSTEP(3,0,1, 1,0, 3,1, 1, 1)

#undef HSTEP
#undef TOURN8
#undef XCOMMIT
#undef XISSUE
}

extern "C" void kernel_launch(void* const* d_in, const int* in_sizes, int n_in,
                              void* d_out, int out_size, void* d_ws, size_t ws_size,
                              hipStream_t stream)
{
    (void)in_sizes; (void)n_in; (void)d_ws; (void)ws_size; (void)out_size;
    const float* x  = (const float*)d_in[0];
    const float* ow = (const float*)d_in[2];   // orient_w (10,2): rows 0..7 = [cos, sin]
    float* out = (float*)d_out;

    dim3 grid(NBANDS, 8, 1);       // 256 blocks = 1 per CU, all resident
    sift_fused<<<grid, 576, 0, stream>>>(x, ow, out);
}

// Round 8
// 95.955 us; speedup vs baseline: 1.2444x; 1.2444x over previous
//
#include <hip/hip_runtime.h>
#include <math.h>

// Fused SIFT-like pipeline:
//   Sobel(3x3, pad1) -> project onto 8 orientations -> argmax -> magnitude
//   into winning bin -> depthwise 4x4 ones conv (pad2) => out (8,8,1025,1025)
//
// v8: full-row band blocks WITH LDS staging (v7's write-locality idea minus
// its confounds). Block = 576 thr (9 waves), covers out cols 0..1024 as 9
// strips of 124 (2 cols/lane); per band of 17 out rows it stages a 22-row
// x slab (padded cols -2..1025) in LDS (90.5 KB), then each wave walks 20
// hist rows reading ~1 fused ds_read2_b64/row + DPP seam. Up to 2 bands
// per block (rb, rb+32). Grid = 256 blocks = 1/CU; bb = k&7 == XCD.
// All writers of any 128B output line are in ONE block -> L2 merges
// partial lines; per-row writes form contiguous 4KB bursts -> page hits.
//
// Per lane: hist cols h0=j0-2+2l,h0+1; out cols oc0=j0+2l,oc0+1.
// out_even = S_l + S_{l+1}; out_odd = B_l + S_{l+1} + A_{l+2}
// (A,B = vertical 4-sums of the lane's 2 hist cols, S=A+B; neighbors via
//  chained DPP wave_shl:1; lanes 62,63 feed only).

#define BAND   17            // out rows per band
#define XROWS  22            // staged x rows = BAND+5
#define LDSC   1028          // padded row: global col g at idx g+2
#define STRIPW 124           // out cols per wave strip
#define PLANE  1050625       // 1025*1025

// DPP wave_shl:1: lane i <- lane i+1, zero-fill at lane 63 (== shfl_down 1)
__device__ __forceinline__ float wshl1(float v) {
    return __int_as_float(
        __builtin_amdgcn_update_dpp(0, __float_as_int(v), 0x130, 0xf, 0xf, true));
}

__global__ __launch_bounds__(576, 3)
void sift_fused(const float* __restrict__ x,
                const float* __restrict__ ow,
                float* __restrict__ out)
{
    __shared__ float sx[XROWS * LDSC];     // 90,464 B

    const int tid  = threadIdx.x;
    const int lane = tid & 63;
    const int wv   = tid >> 6;

    const int k   = blockIdx.x;            // 0..255; HW: XCD = k % 8
    const int bb  = k & 7;                 // batch == XCD
    const int rb0 = k >> 3;                // 0..31

    const float* xb = x + (size_t)bb * 1024 * 1024;

    // orientation weights (uniform loads; exact argmax vs reference)
    float wcn[8], wsn[8];
    #pragma unroll
    for (int o = 0; o < 8; ++o) { wcn[o] = ow[2*o]; wsn[o] = ow[2*o+1]; }

    // lane gather geometry: needs global cols c1+1..c1+3 (B,C,D) + E via DPP
    const int j0 = wv * STRIPW;
    const int c1 = j0 - 4 + 2*lane;
    const int i1 = min(max(c1 + 2, 0), 1024);   // LDS f2 idx -> (A,B), even
    const int i2 = min(max(c1 + 4, 0), 1024);   // LDS f2 idx -> (C,D), even
    const float mB = ((unsigned)(c1+1) < 1024u) ? 1.f : 0.f;
    const float mC = ((unsigned)(c1+2) < 1024u) ? 1.f : 0.f;
    const float mD = ((unsigned)(c1+3) < 1024u) ? 1.f : 0.f;

    // hist col validity
    const int h0 = j0 - 2 + 2*lane;
    const float cm0 = ((unsigned)h0     < 1024u) ? 1.f : 0.f;
    const float cm1 = ((unsigned)(h0+1) < 1024u) ? 1.f : 0.f;

    // store predicates
    const int oc0 = j0 + 2*lane;
    const bool st0 = (2*lane   < STRIPW) && (oc0   <= 1024);
    const bool st1 = (2*lane+1 < STRIPW) && (oc0+1 <= 1024);

    // per-channel plane base pointers (uniform)
    float* po[8];
    #pragma unroll
    for (int o = 0; o < 8; ++o) po[o] = out + (size_t)(bb*8 + o) * PLANE;

    #pragma unroll 1
    for (int half = 0; half < 2; ++half) {
        const int rb = rb0 + 32*half;
        if (rb > 60) break;                // uniform across block
        const int r0 = rb * BAND;

        // ---- stage x slab: rows r0-3 .. r0+18, padded cols -2..1025 ----
        __syncthreads();                   // previous band fully consumed
        for (int s = tid; s < XROWS * 514; s += 576) {
            int sr = s / 514, sc = s - sr*514;   // float2 slot
            int gr_ = r0 - 3 + sr;
            float2 v; v.x = 0.f; v.y = 0.f;
            if ((unsigned)gr_ < 1024u && sc >= 1 && sc <= 512)
                v = *reinterpret_cast<const float2*>(
                        xb + ((size_t)(unsigned)gr_ << 10) + (2*sc - 2));
            *reinterpret_cast<float2*>(&sx[sr*LDSC + 2*sc]) = v;
        }
        __syncthreads();

        int vo   = r0 * 1025 + oc0;
        int orow = r0;
        int hrow = r0 - 2;
        int lr   = 0;                      // staged row idx of next issue

        // x-row d/w rings [slot][col], raw hist ring (m0,m1,packed idx)
        float RD[4][2], RW[4][2];
        float rm[4][2]; int rip[4];
        float2 pv1, pv2;

// issue LDS reads for next staged row (clamped; tail reads unused)
#define XISSUE() { \
    const float* rp_ = &sx[min(lr, XROWS-1) * LDSC]; \
    pv1 = *reinterpret_cast<const float2*>(rp_ + i1); \
    pv2 = *reinterpret_cast<const float2*>(rp_ + i2); \
    lr++; \
}

// commit pending loads into x ring slot SB (masked cols, DPP seam)
#define XCOMMIT(SB) { \
    float B_ = pv1.y * mB, C_ = pv2.x * mC, D_ = pv2.y * mD; \
    float E_ = wshl1(C_); \
    RD[SB][0] = D_ - B_; \
    RD[SB][1] = E_ - C_; \
    RW[SB][0] = B_ + 2.0f*C_ + D_; \
    RW[SB][1] = C_ + 2.0f*D_ + E_; \
}

// tournament argmax: identical semantics to sequential first-max
#define TOURN8(RES, GX, GY) { \
    float pj0 = (GX)*wcn[0] + (GY)*wsn[0]; \
    float pj1 = (GX)*wcn[1] + (GY)*wsn[1]; \
    float pj2 = (GX)*wcn[2] + (GY)*wsn[2]; \
    float pj3 = (GX)*wcn[3] + (GY)*wsn[3]; \
    float pj4 = (GX)*wcn[4] + (GY)*wsn[4]; \
    float pj5 = (GX)*wcn[5] + (GY)*wsn[5]; \
    float pj6 = (GX)*wcn[6] + (GY)*wsn[6]; \
    float pj7 = (GX)*wcn[7] + (GY)*wsn[7]; \
    bool g01 = pj1 > pj0; float b01 = g01 ? pj1 : pj0; int i01 = g01 ? 1 : 0; \
    bool g23 = pj3 > pj2; float b23 = g23 ? pj3 : pj2; int i23 = g23 ? 3 : 2; \
    bool g45 = pj5 > pj4; float b45 = g45 ? pj5 : pj4; int i45 = g45 ? 5 : 4; \
    bool g67 = pj7 > pj6; float b67 = g67 ? pj7 : pj6; int i67 = g67 ? 7 : 6; \
    bool gA = b23 > b01; float bA = gA ? b23 : b01; int iA = gA ? i23 : i01; \
    bool gB = b67 > b45; float bB = gB ? b67 : b45; int iB = gB ? i67 : i45; \
    RES = (bB > bA) ? iB : iA; \
}

// finalize out row using all 4 ring slots (window t-2..t+1): expand to 8
// channels, vertical sums A,B -> S; horizontal via DPP; 2 dword stores.
#define FIN() { \
    bool rowok = (orow <= 1024); \
    int e00 = rip[0] & 7, e01 = rip[0] >> 3; \
    int e10 = rip[1] & 7, e11 = rip[1] >> 3; \
    int e20 = rip[2] & 7, e21 = rip[2] >> 3; \
    int e30 = rip[3] & 7, e31 = rip[3] >> 3; \
    _Pragma("unroll") \
    for (int o = 0; o < 8; ++o) { \
        float a_ = (e00 == o ? rm[0][0] : 0.0f); \
        a_ += (e10 == o ? rm[1][0] : 0.0f); \
        a_ += (e20 == o ? rm[2][0] : 0.0f); \
        a_ += (e30 == o ? rm[3][0] : 0.0f); \
        float b_ = (e01 == o ? rm[0][1] : 0.0f); \
        b_ += (e11 == o ? rm[1][1] : 0.0f); \
        b_ += (e21 == o ? rm[2][1] : 0.0f); \
        b_ += (e31 == o ? rm[3][1] : 0.0f); \
        float S_  = a_ + b_; \
        float Sd_ = wshl1(S_); \
        float Ad2 = wshl1(wshl1(a_)); \
        float Ev  = S_ + Sd_; \
        float Ov  = b_ + Sd_ + Ad2; \
        if (rowok && st0) po[o][vo]   = Ev; \
        if (rowok && st1) po[o][vo+1] = Ov; \
    } \
    vo += 1025; orow++; \
}

// one hist row: commit x row j+2 into SB, issue j+3, Sobel both cols,
// magnitude+argmax into ring slot RS; optional FIN of out row j-3.
#define HSTEP(ST, SM, SB, RS, DOFIN) { \
    XCOMMIT(SB) \
    XISSUE() \
    float rowm = ((unsigned)hrow < 1024u) ? 1.f : 0.f; \
    hrow++; \
    float gx0 = RD[ST][0] + 2.0f*RD[SM][0] + RD[SB][0]; \
    float gy0 = RW[SB][0] - RW[ST][0]; \
    float gx1 = RD[ST][1] + 2.0f*RD[SM][1] + RD[SB][1]; \
    float gy1 = RW[SB][1] - RW[ST][1]; \
    rm[RS][0] = __builtin_amdgcn_sqrtf(gx0*gx0 + gy0*gy0) * (rowm * cm0); \
    rm[RS][1] = __builtin_amdgcn_sqrtf(gx1*gx1 + gy1*gy1) * (rowm * cm1); \
    int i0_, i1_; \
    TOURN8(i0_, gx0, gy0) \
    TOURN8(i1_, gx1, gy1) \
    rip[RS] = i0_ | (i1_ << 3); \
    if (DOFIN) { FIN() } \
}

        // prologue: x rows slots 0,1 committed; hist rows j=0,1,2 (no FIN)
        XISSUE()
        XCOMMIT(0) XISSUE()
        XCOMMIT(1) XISSUE()
        HSTEP(0,1,2, 0, 0)     // j=0
        HSTEP(1,2,3, 1, 0)     // j=1
        HSTEP(2,3,0, 2, 0)     // j=2
        // steady: j=3..18 (4 QUADs), FIN t=j-3
        #pragma unroll 1
        for (int it = 0; it < 4; ++it) {
            HSTEP(3,0,1, 3, 1)     // j%4==3
            HSTEP(0,1,2, 0, 1)     // j%4==0
            HSTEP(1,2,3, 1, 1)     // j%4==1
            HSTEP(2,3,0, 2, 1)     // j%4==2
        }
        // j=19: last FIN -> out row r0+16
        HSTEP(3,0,1, 3, 1)

#undef HSTEP
#undef FIN
#undef TOURN8
#undef XCOMMIT
#undef XISSUE
    }
}

extern "C" void kernel_launch(void* const* d_in, const int* in_sizes, int n_in,
                              void* d_out, int out_size, void* d_ws, size_t ws_size,
                              hipStream_t stream)
{
    (void)in_sizes; (void)n_in; (void)d_ws; (void)ws_size; (void)out_size;
    const float* x  = (const float*)d_in[0];
    const float* ow = (const float*)d_in[2];   // orient_w (10,2): rows 0..7 = [cos, sin]
    float* out = (float*)d_out;

    sift_fused<<<dim3(256, 1, 1), 576, 0, stream>>>(x, ow, out);
}